// Round 7
// baseline (88.408 us; speedup 1.0000x reference)
//
#include <hip/hip_runtime.h>

#define S_LEN 8192
#define DIM   64
#define WIN   64
#define QB    32            // queries per block (shared by all 4 waves)
#define ROWS  160           // QB + 2*WIN staged rows
#define RPW   40            // rows per wave (4-way key-split)
#define CSTRIDE 68          // combine row stride: 64 o + 1 l + pad
#define NXCD  8

// Butterfly add over 8-lane groups, pure VALU (DPP).
// 0xB1=quad_perm xor1; 0x4E=quad_perm xor2; 0x141=row_half_mirror (xor7)
template<int CTRL>
__device__ __forceinline__ float dpp_add(float v) {
    int s = __builtin_amdgcn_update_dpp(0, __float_as_int(v), CTRL, 0xF, 0xF, true);
    return v + __int_as_float(s);
}

// async global->LDS, 16B/lane; LDS dest = wave-uniform base + lane*16
__device__ __forceinline__ void gload16(const float* g, float* l) {
    __builtin_amdgcn_global_load_lds(
        (const __attribute__((address_space(1))) unsigned int*)g,
        (__attribute__((address_space(3))) unsigned int*)l,
        16, 0, 0);
}

__global__ __launch_bounds__(256, 4)
void swa_fwd(const float* __restrict__ qg,
             const float* __restrict__ kg,
             const float* __restrict__ vg,
             float* __restrict__ outg) {
    // K only in LDS: 40 KiB exactly -> 4 blocks/CU (4 waves/SIMD of TLP)
    __shared__ __align__(16) float ks[ROWS * DIM];

    // XCD swizzle: neighbor logical blocks (sharing window rows) on same L2
    const int nwg = gridDim.x;
    const int cpx = nwg / NXCD;
    const int lb  = (blockIdx.x % NXCD) * cpx + blockIdx.x / NXCD;

    const int nqb  = S_LEN / QB;
    const int b    = lb / nqb;
    const int s0   = (lb % nqb) * QB;
    const int tid  = threadIdx.x;
    const int wv   = tid >> 6;          // wave: key-split slice [40wv, 40wv+40)
    const int lane = tid & 63;
    const int g    = lane >> 3;         // 8 groups/wave
    const int sub  = lane & 7;          // dim slice 8*sub..+7
    const int c0   = s0 - WIN;          // first staged row (may be <0)

    // ---- stage own 40-row K slice: 10 gload16, coalesced 1KB/instr.
    // Wave reads only rows it stages itself -> no cross-wave barrier needed.
    // OOB rows: clamp source (finite garbage, masked to e=0 by window check).
    #pragma unroll
    for (int t = 0; t < 10; ++t) {
        int f4 = wv * 640 + t * 64 + lane;
        int gr = c0 + (f4 >> 4);
        gr = gr < 0 ? 0 : (gr > S_LEN - 1 ? S_LEN - 1 : gr);
        int base  = (b * S_LEN + gr) * DIM + ((f4 & 15) << 2);
        gload16(kg + base, ks + wv * 2560 + t * 256);
    }

    // ---- q fragments for this group's 4 queries (same across waves)
    const float qscale = 0.125f * 1.44269504088896340736f;
    float qreg[4][8];
    int vlo[4], vspan[4];
    #pragma unroll
    for (int jj = 0; jj < 4; ++jj) {
        int s = s0 + 4 * g + jj;
        int lo = (s - WIN < 0) ? 0 : (s - WIN);
        int hi = (s + WIN > S_LEN - 1) ? (S_LEN - 1) : (s + WIN);
        vlo[jj] = lo; vspan[jj] = hi - lo;
        const float4* qp = reinterpret_cast<const float4*>(qg + (b * S_LEN + s) * DIM + 8 * sub);
        float4 a = qp[0], c = qp[1];
        qreg[jj][0] = a.x * qscale; qreg[jj][1] = a.y * qscale;
        qreg[jj][2] = a.z * qscale; qreg[jj][3] = a.w * qscale;
        qreg[jj][4] = c.x * qscale; qreg[jj][5] = c.y * qscale;
        qreg[jj][6] = c.z * qscale; qreg[jj][7] = c.w * qscale;
    }

    float l[4] = {0.f, 0.f, 0.f, 0.f};
    float o[4][8] = {};

    // own K slice (and q) landed; other blocks' waves compute meanwhile
    asm volatile("s_waitcnt vmcnt(0)" ::: "memory");
    __builtin_amdgcn_sched_barrier(0);

    const int    rbase  = c0 + wv * RPW;
    const float* kbase  = ks + wv * (RPW * DIM) + 8 * sub;
    const float* vgbase = vg + (b * S_LEN) * DIM + 8 * sub;

    #pragma unroll 2
    for (int rr = 0; rr < RPW; ++rr) {
        const int r  = rbase + rr;
        const int rc = r < 0 ? 0 : (r > S_LEN - 1 ? S_LEN - 1 : r);
        // V straight from global (L1/L2-served, 256B/row per wave); issued
        // early so QK+reduce (~50 instr) covers the latency, plus 4-way TLP.
        const float* vr = vgbase + rc * DIM;
        float4 v0 = *reinterpret_cast<const float4*>(vr);
        float4 v1 = *reinterpret_cast<const float4*>(vr + 4);

        const float* kr = kbase + rr * DIM;
        float4 k0 = *reinterpret_cast<const float4*>(kr);
        float4 k1 = *reinterpret_cast<const float4*>(kr + 4);

        float p[4];
        #pragma unroll
        for (int jj = 0; jj < 4; ++jj)
            p[jj] = qreg[jj][0]*k0.x + qreg[jj][1]*k0.y + qreg[jj][2]*k0.z + qreg[jj][3]*k0.w
                  + qreg[jj][4]*k1.x + qreg[jj][5]*k1.y + qreg[jj][6]*k1.z + qreg[jj][7]*k1.w;
        #pragma unroll
        for (int jj = 0; jj < 4; ++jj) p[jj] = dpp_add<0xB1>(p[jj]);
        #pragma unroll
        for (int jj = 0; jj < 4; ++jj) p[jj] = dpp_add<0x4E>(p[jj]);
        #pragma unroll
        for (int jj = 0; jj < 4; ++jj) p[jj] = dpp_add<0x141>(p[jj]);

        #pragma unroll
        for (int jj = 0; jj < 4; ++jj) {
            bool valid = (unsigned)(r - vlo[jj]) <= (unsigned)vspan[jj];
            float e = valid ? __builtin_amdgcn_exp2f(p[jj]) : 0.f;
            l[jj] += e;
            o[jj][0] += e * v0.x; o[jj][1] += e * v0.y;
            o[jj][2] += e * v0.z; o[jj][3] += e * v0.w;
            o[jj][4] += e * v1.x; o[jj][5] += e * v1.y;
            o[jj][6] += e * v1.z; o[jj][7] += e * v1.w;
        }
    }

    // ---- combine across the 4 key-split waves via LDS (reuses ks: 34.8 KiB)
    __syncthreads();                    // everyone done reading ks
    float* comb = ks;                   // [4 waves][32 q][CSTRIDE]
    #pragma unroll
    for (int jj = 0; jj < 4; ++jj) {
        int qi = 4 * g + jj;
        float* dst = comb + (wv * QB + qi) * CSTRIDE + 8 * sub;
        *reinterpret_cast<float4*>(dst)     = make_float4(o[jj][0], o[jj][1], o[jj][2], o[jj][3]);
        *reinterpret_cast<float4*>(dst + 4) = make_float4(o[jj][4], o[jj][5], o[jj][6], o[jj][7]);
        if (sub == 0) comb[(wv * QB + qi) * CSTRIDE + 64] = l[jj];
    }
    __syncthreads();

    // thread t -> query t>>3, dims (t&7)*8 ..+8
    {
        int qi = tid >> 3;
        int ds = (tid & 7) * 8;
        float acc[8] = {};
        float denom = 0.f;
        #pragma unroll
        for (int w = 0; w < 4; ++w) {
            const float* src = comb + (w * QB + qi) * CSTRIDE;
            denom += src[64];
            float4 a = *reinterpret_cast<const float4*>(src + ds);
            float4 c = *reinterpret_cast<const float4*>(src + ds + 4);
            acc[0] += a.x; acc[1] += a.y; acc[2] += a.z; acc[3] += a.w;
            acc[4] += c.x; acc[5] += c.y; acc[6] += c.z; acc[7] += c.w;
        }
        float inv = 1.0f / denom;
        float* op = outg + (b * S_LEN + s0 + qi) * DIM + ds;
        *reinterpret_cast<float4*>(op)     = make_float4(acc[0]*inv, acc[1]*inv, acc[2]*inv, acc[3]*inv);
        *reinterpret_cast<float4*>(op + 4) = make_float4(acc[4]*inv, acc[5]*inv, acc[6]*inv, acc[7]*inv);
    }
}

extern "C" void kernel_launch(void* const* d_in, const int* in_sizes, int n_in,
                              void* d_out, int out_size, void* d_ws, size_t ws_size,
                              hipStream_t stream) {
    const float* q = (const float*)d_in[0];
    const float* k = (const float*)d_in[1];
    const float* v = (const float*)d_in[2];
    float* out = (float*)d_out;
    int B = in_sizes[0] / (S_LEN * DIM);
    dim3 grid(B * (S_LEN / QB));          // 512 blocks for B=2
    swa_fwd<<<grid, 256, 0, stream>>>(q, k, v, out);
}

// Round 8
// 81.828 us; speedup vs baseline: 1.0804x; 1.0804x over previous
//
#include <hip/hip_runtime.h>

#define S_LEN 8192
#define DIM   64
#define WIN   64
#define QB    32            // queries per block (shared by all 4 waves)
#define ROWS  160           // QB + 2*WIN staged rows
#define RPW   40            // rows per wave (4-way key-split)
#define HALF  20            // rows per pipelined half-slice
#define CSTRIDE 68          // combine row stride: 64 o + 1 l + pad
#define NXCD  8

// Butterfly add over 8-lane groups, pure VALU (DPP).
// 0xB1=quad_perm xor1; 0x4E=quad_perm xor2; 0x141=row_half_mirror (xor7)
template<int CTRL>
__device__ __forceinline__ float dpp_add(float v) {
    int s = __builtin_amdgcn_update_dpp(0, __float_as_int(v), CTRL, 0xF, 0xF, true);
    return v + __int_as_float(s);
}

// async global->LDS, 16B/lane; LDS dest = wave-uniform base + lane*16
__device__ __forceinline__ void gload16(const float* g, float* l) {
    __builtin_amdgcn_global_load_lds(
        (const __attribute__((address_space(1))) unsigned int*)g,
        (__attribute__((address_space(3))) unsigned int*)l,
        16, 0, 0);
}

__global__ __launch_bounds__(256, 2)
void swa_fwd(const float* __restrict__ qg,
             const float* __restrict__ kg,
             const float* __restrict__ vg,
             float* __restrict__ outg) {
    __shared__ __align__(16) float smem[2 * ROWS * DIM];  // 80 KiB -> 2 blocks/CU
    float* ks = smem;
    float* vs = smem + ROWS * DIM;

    // XCD swizzle: neighbor logical blocks (sharing window rows) on same L2
    const int nwg = gridDim.x;
    const int cpx = nwg / NXCD;
    const int lb  = (blockIdx.x % NXCD) * cpx + blockIdx.x / NXCD;

    const int nqb  = S_LEN / QB;
    const int b    = lb / nqb;
    const int s0   = (lb % nqb) * QB;
    const int tid  = threadIdx.x;
    const int wv   = tid >> 6;          // wave: key-split slice [40wv, 40wv+40)
    const int lane = tid & 63;
    const int g    = lane >> 3;         // 8 groups/wave
    const int sub  = lane & 7;          // dim slice 8*sub..+7
    const int c0   = s0 - WIN;          // first staged row (may be <0)

    // ---- q loads FIRST: oldest vmcnt entries, drain before any staging wait
    const float qscale = 0.125f * 1.44269504088896340736f;
    float4 qa[4], qb[4];
    #pragma unroll
    for (int jj = 0; jj < 4; ++jj) {
        int s = s0 + 4 * g + jj;
        const float4* qp = reinterpret_cast<const float4*>(qg + (b * S_LEN + s) * DIM + 8 * sub);
        qa[jj] = qp[0]; qb[jj] = qp[1];
    }
    __builtin_amdgcn_sched_barrier(0);  // pin q loads ahead of staging issues

    // ---- stage own 40-row slice in two pipelined halves (10 gload16 each).
    // Wave reads only rows it stages itself -> no cross-wave barrier.
    // OOB rows: clamp source (finite garbage, masked to e=0 by window check).
    #pragma unroll
    for (int t = 0; t < 5; ++t) {       // half A: rows [40wv, 40wv+20)
        int f4 = wv * 640 + t * 64 + lane;
        int gr = c0 + (f4 >> 4);
        gr = gr < 0 ? 0 : (gr > S_LEN - 1 ? S_LEN - 1 : gr);
        int base = (b * S_LEN + gr) * DIM + ((f4 & 15) << 2);
        gload16(kg + base, ks + wv * 2560 + t * 256);
        gload16(vg + base, vs + wv * 2560 + t * 256);
    }
    #pragma unroll
    for (int t = 5; t < 10; ++t) {      // half B: rows [40wv+20, 40wv+40)
        int f4 = wv * 640 + t * 64 + lane;
        int gr = c0 + (f4 >> 4);
        gr = gr < 0 ? 0 : (gr > S_LEN - 1 ? S_LEN - 1 : gr);
        int base = (b * S_LEN + gr) * DIM + ((f4 & 15) << 2);
        gload16(kg + base, ks + wv * 2560 + t * 256);
        gload16(vg + base, vs + wv * 2560 + t * 256);
    }

    // ---- q fragments (compiler waits only on the q loads here: vmcnt(20))
    float qreg[4][8];
    int vlo[4], vspan[4];
    #pragma unroll
    for (int jj = 0; jj < 4; ++jj) {
        int s = s0 + 4 * g + jj;
        int lo = (s - WIN < 0) ? 0 : (s - WIN);
        int hi = (s + WIN > S_LEN - 1) ? (S_LEN - 1) : (s + WIN);
        vlo[jj] = lo; vspan[jj] = hi - lo;
        qreg[jj][0] = qa[jj].x * qscale; qreg[jj][1] = qa[jj].y * qscale;
        qreg[jj][2] = qa[jj].z * qscale; qreg[jj][3] = qa[jj].w * qscale;
        qreg[jj][4] = qb[jj].x * qscale; qreg[jj][5] = qb[jj].y * qscale;
        qreg[jj][6] = qb[jj].z * qscale; qreg[jj][7] = qb[jj].w * qscale;
    }

    float l[4] = {0.f, 0.f, 0.f, 0.f};
    float o[4][8] = {};

    const int    rbase = c0 + wv * RPW;
    const float* kbase = ks + wv * (RPW * DIM) + 8 * sub;
    const float* vbase = vs + wv * (RPW * DIM) + 8 * sub;

    auto body = [&](int rr) {
        const int r = rbase + rr;
        const float* kr = kbase + rr * DIM;
        const float* vr = vbase + rr * DIM;
        float4 k0 = *reinterpret_cast<const float4*>(kr);
        float4 k1 = *reinterpret_cast<const float4*>(kr + 4);
        float4 v0 = *reinterpret_cast<const float4*>(vr);
        float4 v1 = *reinterpret_cast<const float4*>(vr + 4);

        float p[4];
        #pragma unroll
        for (int jj = 0; jj < 4; ++jj)
            p[jj] = qreg[jj][0]*k0.x + qreg[jj][1]*k0.y + qreg[jj][2]*k0.z + qreg[jj][3]*k0.w
                  + qreg[jj][4]*k1.x + qreg[jj][5]*k1.y + qreg[jj][6]*k1.z + qreg[jj][7]*k1.w;
        #pragma unroll
        for (int jj = 0; jj < 4; ++jj) p[jj] = dpp_add<0xB1>(p[jj]);
        #pragma unroll
        for (int jj = 0; jj < 4; ++jj) p[jj] = dpp_add<0x4E>(p[jj]);
        #pragma unroll
        for (int jj = 0; jj < 4; ++jj) p[jj] = dpp_add<0x141>(p[jj]);

        #pragma unroll
        for (int jj = 0; jj < 4; ++jj) {
            bool valid = (unsigned)(r - vlo[jj]) <= (unsigned)vspan[jj];
            float e = valid ? __builtin_amdgcn_exp2f(p[jj]) : 0.f;
            l[jj] += e;
            o[jj][0] += e * v0.x; o[jj][1] += e * v0.y;
            o[jj][2] += e * v0.z; o[jj][3] += e * v0.w;
            o[jj][4] += e * v1.x; o[jj][5] += e * v1.y;
            o[jj][6] += e * v1.z; o[jj][7] += e * v1.w;
        }
    };

    // ---- half A landed (q + 10 oldest staging); half B still in flight
    asm volatile("s_waitcnt vmcnt(10)" ::: "memory");
    __builtin_amdgcn_sched_barrier(0);
    __builtin_amdgcn_s_setprio(1);
    #pragma unroll 2
    for (int rr = 0; rr < HALF; ++rr) body(rr);
    __builtin_amdgcn_s_setprio(0);

    // ---- half B landed
    asm volatile("s_waitcnt vmcnt(0)" ::: "memory");
    __builtin_amdgcn_sched_barrier(0);
    __builtin_amdgcn_s_setprio(1);
    #pragma unroll 2
    for (int rr = HALF; rr < RPW; ++rr) body(rr);
    __builtin_amdgcn_s_setprio(0);

    // ---- combine across the 4 key-split waves via LDS
    __syncthreads();                    // everyone done reading K/V
    float* comb = smem;                 // [4 waves][32 q][CSTRIDE] = 34.8 KiB
    #pragma unroll
    for (int jj = 0; jj < 4; ++jj) {
        int qi = 4 * g + jj;
        float* dst = comb + (wv * QB + qi) * CSTRIDE + 8 * sub;
        *reinterpret_cast<float4*>(dst)     = make_float4(o[jj][0], o[jj][1], o[jj][2], o[jj][3]);
        *reinterpret_cast<float4*>(dst + 4) = make_float4(o[jj][4], o[jj][5], o[jj][6], o[jj][7]);
        if (sub == 0) comb[(wv * QB + qi) * CSTRIDE + 64] = l[jj];
    }
    __syncthreads();

    // thread t -> query t>>3, dims (t&7)*8 ..+8
    {
        int qi = tid >> 3;
        int ds = (tid & 7) * 8;
        float acc[8] = {};
        float denom = 0.f;
        #pragma unroll
        for (int w = 0; w < 4; ++w) {
            const float* src = comb + (w * QB + qi) * CSTRIDE;
            denom += src[64];
            float4 a = *reinterpret_cast<const float4*>(src + ds);
            float4 c = *reinterpret_cast<const float4*>(src + ds + 4);
            acc[0] += a.x; acc[1] += a.y; acc[2] += a.z; acc[3] += a.w;
            acc[4] += c.x; acc[5] += c.y; acc[6] += c.z; acc[7] += c.w;
        }
        float inv = 1.0f / denom;
        float* op = outg + (b * S_LEN + s0 + qi) * DIM + ds;
        *reinterpret_cast<float4*>(op)     = make_float4(acc[0]*inv, acc[1]*inv, acc[2]*inv, acc[3]*inv);
        *reinterpret_cast<float4*>(op + 4) = make_float4(acc[4]*inv, acc[5]*inv, acc[6]*inv, acc[7]*inv);
    }
}

extern "C" void kernel_launch(void* const* d_in, const int* in_sizes, int n_in,
                              void* d_out, int out_size, void* d_ws, size_t ws_size,
                              hipStream_t stream) {
    const float* q = (const float*)d_in[0];
    const float* k = (const float*)d_in[1];
    const float* v = (const float*)d_in[2];
    float* out = (float*)d_out;
    int B = in_sizes[0] / (S_LEN * DIM);
    dim3 grid(B * (S_LEN / QB));          // 512 blocks for B=2
    swa_fwd<<<grid, 256, 0, stream>>>(q, k, v, out);
}

// Round 9
// 79.614 us; speedup vs baseline: 1.1105x; 1.0278x over previous
//
#include <hip/hip_runtime.h>

#define S_LEN 8192
#define DIM   64
#define WIN   64
#define QB    64            // queries per block (8 waves x 8 queries)
#define ROWS  192           // QB + 2*WIN staged rows
#define JCOUNT 136          // rows per wave: 8 + 2*WIN
#define NXCD  8

// Butterfly add over 8-lane groups, pure VALU (DPP).
// 0xB1=quad_perm xor1; 0x4E=quad_perm xor2; 0x141=row_half_mirror (xor7)
template<int CTRL>
__device__ __forceinline__ float dpp_add(float v) {
    int s = __builtin_amdgcn_update_dpp(0, __float_as_int(v), CTRL, 0xF, 0xF, true);
    return v + __int_as_float(s);
}

// async global->LDS, 16B/lane; LDS dest = wave-uniform base + lane*16
__device__ __forceinline__ void gload16(const float* g, float* l) {
    __builtin_amdgcn_global_load_lds(
        (const __attribute__((address_space(1))) unsigned int*)g,
        (__attribute__((address_space(3))) unsigned int*)l,
        16, 0, 0);
}

__global__ __launch_bounds__(512, 2)
void swa_fwd(const float* __restrict__ qg,
             const float* __restrict__ kg,
             const float* __restrict__ vg,
             float* __restrict__ outg) {
    // 192 rows of K and V: 96 KiB -> 1 block/CU (8 waves = 2/SIMD)
    __shared__ __align__(16) float ks[ROWS * DIM];
    __shared__ __align__(16) float vs[ROWS * DIM];

    // XCD swizzle: neighbor logical blocks (sharing window rows) on same L2
    const int nwg = gridDim.x;          // 256 (multiple of 8 -> bijective)
    const int cpx = nwg / NXCD;
    const int lb  = (blockIdx.x % NXCD) * cpx + blockIdx.x / NXCD;

    const int nqb  = S_LEN / QB;        // 128 query-blocks per batch
    const int b    = lb / nqb;
    const int s0   = (lb % nqb) * QB;
    const int tid  = threadIdx.x;
    const int wv   = tid >> 6;          // wave 0..7 -> queries s0+8*wv..+7
    const int lane = tid & 63;
    const int g    = lane >> 3;         // group 0..7 -> one query
    const int sub  = lane & 7;          // dim slice 8*sub..+7
    const int c0   = s0 - WIN;          // first staged row (may be <0)
    const int q    = s0 + 8 * wv + g;

    // ---- q fragment first (oldest vmcnt entries; drained by the barrier)
    const float* qp = qg + (b * S_LEN + q) * DIM + 8 * sub;
    float4 qa = *reinterpret_cast<const float4*>(qp);
    float4 qb = *reinterpret_cast<const float4*>(qp + 4);
    __builtin_amdgcn_sched_barrier(0);

    // ---- stage 192 rows of K and V: 3072 f4/tensor, 6 gload16 each/thread.
    // OOB rows: clamp source (finite garbage, masked to e=0 by window check).
    #pragma unroll
    for (int t = 0; t < 6; ++t) {
        int f4 = tid + t * 512;         // 0..3071
        int gr = c0 + (f4 >> 4);
        gr = gr < 0 ? 0 : (gr > S_LEN - 1 ? S_LEN - 1 : gr);
        int base  = (b * S_LEN + gr) * DIM + ((f4 & 15) << 2);
        int lbase = (t * 512 + wv * 64) << 2;   // wave-uniform float offset
        gload16(kg + base, ks + lbase);
        gload16(vg + base, vs + lbase);
    }

    // q pre-scaled by D^-0.5 * log2(e): score->prob is one v_exp_f32
    const float qscale = 0.125f * 1.44269504088896340736f;
    float qr[8];
    qr[0] = qa.x * qscale; qr[1] = qa.y * qscale;
    qr[2] = qa.z * qscale; qr[3] = qa.w * qscale;
    qr[4] = qb.x * qscale; qr[5] = qb.y * qscale;
    qr[6] = qb.z * qscale; qr[7] = qb.w * qscale;

    // valid j range: r(j) = c0 + 8*wv + j must lie in [q-WIN, q+WIN] ∩ [0,S)
    const int jlo = max(g, WIN - s0 - 8 * wv);
    const int jhi = min(g + 2 * WIN, S_LEN - 1 - s0 + WIN - 8 * wv);
    const unsigned jspan = (unsigned)(jhi - jlo);

    __syncthreads();                    // all K/V staged (drains vmcnt too)

    const float* kbase = ks + (8 * wv) * DIM + 8 * sub;
    const float* vbase = vs + (8 * wv) * DIM + 8 * sub;

    float l = 0.f;
    float o[8] = {0.f, 0.f, 0.f, 0.f, 0.f, 0.f, 0.f, 0.f};

    #pragma unroll 4
    for (int j = 0; j < JCOUNT; ++j) {
        const float* kr = kbase + j * DIM;
        const float* vr = vbase + j * DIM;
        float4 k0 = *reinterpret_cast<const float4*>(kr);
        float4 k1 = *reinterpret_cast<const float4*>(kr + 4);
        float4 v0 = *reinterpret_cast<const float4*>(vr);
        float4 v1 = *reinterpret_cast<const float4*>(vr + 4);

        float p = qr[0]*k0.x + qr[1]*k0.y + qr[2]*k0.z + qr[3]*k0.w
                + qr[4]*k1.x + qr[5]*k1.y + qr[6]*k1.z + qr[7]*k1.w;
        p = dpp_add<0xB1>(p);
        p = dpp_add<0x4E>(p);
        p = dpp_add<0x141>(p);

        float e = ((unsigned)(j - jlo) <= jspan) ? __builtin_amdgcn_exp2f(p) : 0.f;
        l += e;
        o[0] += e * v0.x; o[1] += e * v0.y; o[2] += e * v0.z; o[3] += e * v0.w;
        o[4] += e * v1.x; o[5] += e * v1.y; o[6] += e * v1.z; o[7] += e * v1.w;
    }

    const float inv = 1.0f / l;
    float* op = outg + (b * S_LEN + q) * DIM + 8 * sub;
    *reinterpret_cast<float4*>(op)     = make_float4(o[0]*inv, o[1]*inv, o[2]*inv, o[3]*inv);
    *reinterpret_cast<float4*>(op + 4) = make_float4(o[4]*inv, o[5]*inv, o[6]*inv, o[7]*inv);
}

extern "C" void kernel_launch(void* const* d_in, const int* in_sizes, int n_in,
                              void* d_out, int out_size, void* d_ws, size_t ws_size,
                              hipStream_t stream) {
    const float* q = (const float*)d_in[0];
    const float* k = (const float*)d_in[1];
    const float* v = (const float*)d_in[2];
    float* out = (float*)d_out;
    int B = in_sizes[0] / (S_LEN * DIM);
    dim3 grid(B * (S_LEN / QB));          // 256 blocks for B=2
    swa_fwd<<<grid, 512, 0, stream>>>(q, k, v, out);
}